// Round 3
// baseline (521.951 us; speedup 1.0000x reference)
//
#include <hip/hip_runtime.h>
#include <hip/hip_bf16.h>

// Problem constants (from reference): N=32, T=2048, D_ENC=D_DEC=U=1024
#define NB 32
#define TD 2048
#define DIM 1024

typedef _Float16 v8h __attribute__((ext_vector_type(8)));
typedef _Float16 v4h __attribute__((ext_vector_type(4)));
typedef float    v4f __attribute__((ext_vector_type(4)));

__device__ __forceinline__ float ftanh(float x) {
    x = fminf(15.f, fmaxf(-15.f, x));
    float e = __expf(2.f * x);
    return (e - 1.f) / (e + 1.f);
}

__device__ __forceinline__ void gld_lds16(const void* g, void* l) {
    __builtin_amdgcn_global_load_lds(
        (const __attribute__((address_space(1))) unsigned int*)g,
        (__attribute__((address_space(3))) unsigned int*)l, 16, 0, 0);
}

// ---------------- K1 (fused): prep = pq (blocks 0..127) + cvt (blocks 128..33407) ----
// pq part: block b owns u-rows b*8..b*8+7 for ALL 32 n -> Wq read ONCE globally
// (4 MB vs old 128 MB). Placed first so it overlaps cvt's HBM shadow.
__global__ __launch_bounds__(256) void prep_kernel(
        const float* __restrict__ enc, const float* __restrict__ Wk,
        const float* __restrict__ queries, const float* __restrict__ Wq,
        const int* __restrict__ lengths,
        _Float16* __restrict__ ench, _Float16* __restrict__ wkh,
        float* __restrict__ pq) {
    int bid = blockIdx.x;
    if (bid < 128) {
        // ---- pq: 4 waves x 2 u-rows = 8 u per block ----
        int lane = threadIdx.x & 63;
        int wv   = threadIdx.x >> 6;
        int u    = bid * 8 + wv * 2;
        const float* w0 = Wq + (size_t)u * DIM;
        const float* w1 = w0 + DIM;
        // lane owns d-slices {j*256 + lane*4 .. +4}, coalesced float4
        float4 wq0[4], wq1[4];
#pragma unroll
        for (int j = 0; j < 4; ++j) {
            wq0[j] = *(const float4*)(w0 + j * 256 + lane * 4);
            wq1[j] = *(const float4*)(w1 + j * 256 + lane * 4);
        }
        for (int n = 0; n < NB; ++n) {
            const float* qn = queries + (size_t)n * DIM;
            float s0 = 0.f, s1 = 0.f;
#pragma unroll
            for (int j = 0; j < 4; ++j) {
                float4 qv = *(const float4*)(qn + j * 256 + lane * 4);
                s0 += qv.x * wq0[j].x + qv.y * wq0[j].y + qv.z * wq0[j].z + qv.w * wq0[j].w;
                s1 += qv.x * wq1[j].x + qv.y * wq1[j].y + qv.z * wq1[j].z + qv.w * wq1[j].w;
            }
#pragma unroll
            for (int off = 32; off >= 1; off >>= 1) {
                s0 += __shfl_xor(s0, off);
                s1 += __shfl_xor(s1, off);
            }
            if (lane == 0) {
                pq[(size_t)n * DIM + u]     = s0;
                pq[(size_t)n * DIM + u + 1] = s1;
            }
        }
        return;
    }
    // ---- cvt: f32 -> f16, 2 rows per block ----
    int cb = bid - 128;
    int local = threadIdx.x * 8;              // 0..2047 within the 2-row pair
    int rsub  = local >> 10;                  // 0 or 1
    int col   = local & 1023;
    const float* src;
    _Float16* dst;
    size_t row;
    if (cb < 32768) {
        row = (size_t)cb * 2 + rsub;          // enc row in [0, 65536)
        int n = (int)(row >> 11), t = (int)(row & 2047);
        if (t >= lengths[n]) return;          // masked row: never read downstream
        src = enc; dst = ench;
    } else {
        row = (size_t)(cb - 32768) * 2 + rsub;  // Wk row in [0,1024)
        src = Wk; dst = wkh;
    }
    const float4* s = (const float4*)(src + row * DIM + col);
    float4 a = s[0], b = s[1];
    v8h h;
    h[0] = (_Float16)a.x; h[1] = (_Float16)a.y; h[2] = (_Float16)a.z; h[3] = (_Float16)a.w;
    h[4] = (_Float16)b.x; h[5] = (_Float16)b.y; h[6] = (_Float16)b.z; h[7] = (_Float16)b.w;
    *(v8h*)(dst + row * DIM + col) = h;
}

// ---------------- K1 (fallback path): standalone pq ----------------
__global__ __launch_bounds__(256) void pq_kernel(const float* __restrict__ q,
                                                 const float* __restrict__ Wq,
                                                 float* __restrict__ pq) {
    int wid  = blockIdx.x * 4 + (threadIdx.x >> 6);
    int lane = threadIdx.x & 63;
    int n = wid >> 10;
    int u = wid & 1023;
    const float4* qr = (const float4*)(q  + (size_t)n * DIM);
    const float4* wr = (const float4*)(Wq + (size_t)u * DIM);
    float s = 0.f;
#pragma unroll
    for (int j = 0; j < 4; ++j) {
        int i = lane + 64 * j;
        float4 a = qr[i], b = wr[i];
        s += a.x * b.x + a.y * b.y + a.z * b.z + a.w * b.w;
    }
#pragma unroll
    for (int off = 32; off >= 1; off >>= 1) s += __shfl_xor(s, off);
    if (lane == 0) pq[(size_t)n * DIM + u] = s;
}

// ---------------- K2 (fast v3): m97-style single-buffer, BK=64, swizzled ----------------
// grid = 4096 (1-D). Per block: one 128x128 output tile (bm, bn).
// XCD-balanced swizzle: bm = ((idx>>3)<<3)|xcd; 8 bn-blocks of one bm consecutive
// on one XCD -> A-tile L2-resident across its 8 uses. T2 swizzle: 0 bank conflicts
// (measured round 1). Loop structure = m97 drain + TLP (evidence: 874 vs 622-682
// for 2-phase at 128^2) -- intentionally unchanged this round.
__global__ __launch_bounds__(256) void gemm_tanh_h3(
        const _Float16* __restrict__ ench, const _Float16* __restrict__ wkh,
        const float* __restrict__ pq, const float* __restrict__ v,
        const int* __restrict__ lengths, float* __restrict__ weights) {
    const int bid = blockIdx.x;
    const int xcd = bid & 7;
    const int idx = bid >> 3;
    const int bm  = ((idx >> 3) << 3) | xcd;   // [0,512), ≡ xcd (mod 8)
    const int bn  = idx & 7;
    const int rowBase = bm * 128;
    const int n = rowBase >> 11;
    const int tstart = rowBase & 2047;
    if (lengths[n] <= tstart) return;

    __shared__ _Float16 As[128 * 64];   // 16 KB
    __shared__ _Float16 Bs[128 * 64];   // 16 KB

    const int tid  = threadIdx.x;
    const int lane = tid & 63;
    const int wv   = tid >> 6;
    const int wm   = wv >> 1, wn = wv & 1;   // 2x2 waves, 64x64 each
    const int q4   = lane >> 4;
    const int l16  = lane & 15;

    // epilogue operands hoisted above the K-loop (independent of it)
    float pqv[4], vv[4];
#pragma unroll
    for (int nt = 0; nt < 4; ++nt) {
        int ug = bn * 128 + wn * 64 + nt * 16 + l16;
        pqv[nt] = pq[(size_t)n * DIM + ug];
        vv[nt]  = v[ug];
    }

    // staging: lane l -> row sr=l>>3, LDS slot sl=l&7; global slot pre-swizzled
    // sl^sr so that LDS[r][s] = G[r][s ^ (r&7)] with a LINEAR LDS dest (rule #21).
    const int sr  = lane >> 3;
    const int scs = (lane & 7) ^ sr;

    const _Float16* Ag = ench + (size_t)(rowBase + wv * 32 + sr) * DIM + scs * 8;
    const _Float16* Bg = wkh + (size_t)(bn * 128 + wv * 32 + sr) * DIM + scs * 8;
    _Float16* Al = &As[(wv * 32) * 64];
    _Float16* Bl = &Bs[(wv * 32) * 64];

    v4f acc[4][4];
    const v4f vz = {0.f, 0.f, 0.f, 0.f};
#pragma unroll
    for (int i = 0; i < 4; ++i)
#pragma unroll
        for (int j = 0; j < 4; ++j) acc[i][j] = vz;

    for (int k0 = 0; k0 < DIM; k0 += 64) {
        __syncthreads();                       // all reads of LDS done
#pragma unroll
        for (int j = 0; j < 4; ++j) {
            gld_lds16(Ag + k0 + j * 8 * DIM, Al + j * 8 * 64);
            gld_lds16(Bg + k0 + j * 8 * DIM, Bl + j * 8 * 64);
        }
        __syncthreads();                       // drains vmcnt(0): tile visible

#pragma unroll
        for (int kk = 0; kk < 2; ++kk) {
            v8h a[4], b[4];
#pragma unroll
            for (int mt = 0; mt < 4; ++mt) {
                int r = wm * 64 + mt * 16 + l16;
                a[mt] = *(const v8h*)(&As[r * 64 + (((kk * 4 + q4) ^ (r & 7)) * 8)]);
            }
#pragma unroll
            for (int nt = 0; nt < 4; ++nt) {
                int r = wn * 64 + nt * 16 + l16;
                b[nt] = *(const v8h*)(&Bs[r * 64 + (((kk * 4 + q4) ^ (r & 7)) * 8)]);
            }
#pragma unroll
            for (int mt = 0; mt < 4; ++mt)
#pragma unroll
                for (int nt = 0; nt < 4; ++nt)
                    acc[mt][nt] = __builtin_amdgcn_mfma_f32_16x16x32_f16(
                        a[mt], b[nt], acc[mt][nt], 0, 0, 0);
        }
    }

#pragma unroll
    for (int mt = 0; mt < 4; ++mt) {
#pragma unroll
        for (int r = 0; r < 4; ++r) {
            float s = 0.f;
#pragma unroll
            for (int nt = 0; nt < 4; ++nt)
                s += ftanh(acc[mt][nt][r] + pqv[nt]) * vv[nt];
            s += __shfl_xor(s, 1);
            s += __shfl_xor(s, 2);
            s += __shfl_xor(s, 4);
            s += __shfl_xor(s, 8);
            if (l16 == 0) {
                int R = rowBase + wm * 64 + mt * 16 + q4 * 4 + r;
                atomicAdd(&weights[R], s);
            }
        }
    }
}

// ---------------- K2 (fallback): inline-convert f32 GEMM ----------------
__global__ __launch_bounds__(256) void gemm_tanh_kernel(
        const float* __restrict__ enc, const float* __restrict__ Wk,
        const float* __restrict__ pq,  const float* __restrict__ v,
        const int* __restrict__ lengths, float* __restrict__ weights) {
    const int bm = blockIdx.x;
    const int bn = blockIdx.y;
    const int rowBase = bm * 128;
    const int n = rowBase >> 11;
    const int tstart = rowBase & 2047;
    if (lengths[n] <= tstart) return;

    __shared__ _Float16 As[128 * 40];
    __shared__ _Float16 Bs[128 * 40];

    const int tid  = threadIdx.x;
    const int lane = tid & 63;
    const int wv   = tid >> 6;
    const int wm   = wv >> 1, wn = wv & 1;
    const int q4   = lane >> 4;
    const int l16  = lane & 15;

    v4f acc[4][4];
    const v4f vz = {0.f, 0.f, 0.f, 0.f};
#pragma unroll
    for (int i = 0; i < 4; ++i)
#pragma unroll
        for (int j = 0; j < 4; ++j) acc[i][j] = vz;

    const int srow = tid >> 3;
    const int skc  = (tid & 7) * 4;

    for (int k0 = 0; k0 < DIM; k0 += 32) {
        __syncthreads();
#pragma unroll
        for (int j = 0; j < 4; ++j) {
            int row = j * 32 + srow;
            float4 av = *(const float4*)(enc + (size_t)(rowBase + row) * DIM + k0 + skc);
            v4h ah;
            ah.x = (_Float16)av.x; ah.y = (_Float16)av.y;
            ah.z = (_Float16)av.z; ah.w = (_Float16)av.w;
            *(v4h*)(&As[row * 40 + skc]) = ah;
            float4 bv = *(const float4*)(Wk + (size_t)(bn * 128 + row) * DIM + k0 + skc);
            v4h bh;
            bh.x = (_Float16)bv.x; bh.y = (_Float16)bv.y;
            bh.z = (_Float16)bv.z; bh.w = (_Float16)bv.w;
            *(v4h*)(&Bs[row * 40 + skc]) = bh;
        }
        __syncthreads();

        v8h afr[4], bfr[4];
#pragma unroll
        for (int mt = 0; mt < 4; ++mt)
            afr[mt] = *(const v8h*)(&As[(wm * 64 + mt * 16 + l16) * 40 + q4 * 8]);
#pragma unroll
        for (int nt = 0; nt < 4; ++nt)
            bfr[nt] = *(const v8h*)(&Bs[(wn * 64 + nt * 16 + l16) * 40 + q4 * 8]);
#pragma unroll
        for (int mt = 0; mt < 4; ++mt)
#pragma unroll
            for (int nt = 0; nt < 4; ++nt)
                acc[mt][nt] = __builtin_amdgcn_mfma_f32_16x16x32_f16(
                    afr[mt], bfr[nt], acc[mt][nt], 0, 0, 0);
    }

    float pqv[4], vv[4];
#pragma unroll
    for (int nt = 0; nt < 4; ++nt) {
        int ug = bn * 128 + wn * 64 + nt * 16 + l16;
        pqv[nt] = pq[(size_t)n * DIM + ug];
        vv[nt]  = v[ug];
    }
#pragma unroll
    for (int mt = 0; mt < 4; ++mt) {
#pragma unroll
        for (int r = 0; r < 4; ++r) {
            float s = 0.f;
#pragma unroll
            for (int nt = 0; nt < 4; ++nt)
                s += ftanh(acc[mt][nt][r] + pqv[nt]) * vv[nt];
            s += __shfl_xor(s, 1);
            s += __shfl_xor(s, 2);
            s += __shfl_xor(s, 4);
            s += __shfl_xor(s, 8);
            if (l16 == 0) {
                int R = rowBase + wm * 64 + mt * 16 + q4 * 4 + r;
                atomicAdd(&weights[R], s);
            }
        }
    }
}

// ---------------- K3: masked softmax per n-row, in place ----------------
__global__ __launch_bounds__(256) void softmax_kernel(float* __restrict__ w,
                                                      const int* __restrict__ lengths) {
    int n = blockIdx.x;
    int len = lengths[n];
    float* row = w + (size_t)n * TD;
    int tid = threadIdx.x;
    float wv[8], ev[8];
    float mx = -INFINITY;
#pragma unroll
    for (int i = 0; i < 8; ++i) {
        int t = tid + i * 256;
        float x = row[t];
        x = (t < len) ? x : -INFINITY;
        wv[i] = x;
        mx = fmaxf(mx, x);
    }
#pragma unroll
    for (int off = 32; off >= 1; off >>= 1) mx = fmaxf(mx, __shfl_xor(mx, off));
    __shared__ float redm[4], reds[4];
    int lane = tid & 63, wvid = tid >> 6;
    if (lane == 0) redm[wvid] = mx;
    __syncthreads();
    mx = fmaxf(fmaxf(redm[0], redm[1]), fmaxf(redm[2], redm[3]));
    float sm = 0.f;
#pragma unroll
    for (int i = 0; i < 8; ++i) { ev[i] = __expf(wv[i] - mx); sm += ev[i]; }
#pragma unroll
    for (int off = 32; off >= 1; off >>= 1) sm += __shfl_xor(sm, off);
    if (lane == 0) reds[wvid] = sm;
    __syncthreads();
    sm = reds[0] + reds[1] + reds[2] + reds[3];
    float inv = 1.f / sm;
#pragma unroll
    for (int i = 0; i < 8; ++i) row[tid + i * 256] = ev[i] * inv;
}

// ---------------- K4 (fast v4): contexts, 64-t chunks, 2x parallelism ----------------
// 32 blocks per n -> ~2 active blocks/CU (was ~1), half-length dependency chains.
__global__ __launch_bounds__(256) void ctx_kernel_h4(const float* __restrict__ align,
                                                     const _Float16* __restrict__ ench,
                                                     const int* __restrict__ lengths,
                                                     float* __restrict__ ctx) {
    int n  = blockIdx.y;
    int t0 = blockIdx.x * 64;
    int len = lengths[n];
    if (len <= t0) return;
    int half = threadIdx.x >> 7;          // 0/1: t parity
    int col  = (threadIdx.x & 127) * 8;   // 8 cols -> 16B f16 loads
    float acc[8];
#pragma unroll
    for (int i = 0; i < 8; ++i) acc[i] = 0.f;
    int tend = min(t0 + 64, len);         // only converted (valid) rows
    const float* arow = align + (size_t)n * TD;
    const _Float16* ebase = ench + (size_t)n * TD * DIM + col;
#pragma unroll 2
    for (int t = t0 + half; t < tend; t += 2) {
        float a = arow[t];
        v8h e = *(const v8h*)(ebase + (size_t)t * DIM);
#pragma unroll
        for (int i = 0; i < 8; ++i) acc[i] += a * (float)e[i];
    }
    __shared__ float cred[DIM];
    if (half == 1) {
#pragma unroll
        for (int i = 0; i < 8; ++i) cred[col + i] = acc[i];
    }
    __syncthreads();
    if (half == 0) {
        float* c = ctx + (size_t)n * DIM + col;
#pragma unroll
        for (int i = 0; i < 8; ++i) atomicAdd(c + i, acc[i] + cred[col + i]);
    }
}

// ---------------- K4 (fallback): f32 enc ----------------
__global__ __launch_bounds__(256) void ctx_kernel(const float* __restrict__ align,
                                                  const float* __restrict__ enc,
                                                  const int* __restrict__ lengths,
                                                  float* __restrict__ ctx) {
    int n  = blockIdx.y;
    int t0 = blockIdx.x * 128;
    if (lengths[n] <= t0) return;
    int e = threadIdx.x * 4;
    float4 acc = make_float4(0.f, 0.f, 0.f, 0.f);
    const float* arow = align + (size_t)n * TD;
    const float* erow = enc + (size_t)n * TD * DIM;
    for (int tt = 0; tt < 128; ++tt) {
        int t = t0 + tt;
        float a = arow[t];
        if (a != 0.f) {
            float4 evv = *(const float4*)(erow + (size_t)t * DIM + e);
            acc.x += a * evv.x; acc.y += a * evv.y;
            acc.z += a * evv.z; acc.w += a * evv.w;
        }
    }
    float* c = ctx + (size_t)n * DIM + e;
    atomicAdd(c + 0, acc.x);
    atomicAdd(c + 1, acc.y);
    atomicAdd(c + 2, acc.z);
    atomicAdd(c + 3, acc.w);
}

extern "C" void kernel_launch(void* const* d_in, const int* in_sizes, int n_in,
                              void* d_out, int out_size, void* d_ws, size_t ws_size,
                              hipStream_t stream) {
    const float* queries = (const float*)d_in[0];   // [32,1,1024]
    const float* enc     = (const float*)d_in[1];   // [32,2048,1024]
    const int*   lengths = (const int*)d_in[2];     // [32]
    const float* v       = (const float*)d_in[3];   // [1024]
    const float* Wq      = (const float*)d_in[4];   // [1024,1024]
    const float* Wk      = (const float*)d_in[5];   // [1024,1024]

    float* out = (float*)d_out;
    float* ctx = out;                // [32,1024]  (also temp home of pq)
    float* alg = out + NB * DIM;     // [32,2048]  (weights -> alignments in place)
    float* pq  = ctx;                // pq fully consumed before ctx memset below
    (void)in_sizes; (void)n_in; (void)out_size;

    const size_t ench_elems = (size_t)NB * TD * DIM;
    const size_t need = (ench_elems + (size_t)DIM * DIM) * sizeof(_Float16);

    hipMemsetAsync(alg, 0, (size_t)NB * TD * sizeof(float), stream);

    if (ws_size >= need) {
        _Float16* ench = (_Float16*)d_ws;
        _Float16* wkh  = ench + ench_elems;
        // fused pq + cvt: pq blocks first so they overlap cvt's HBM shadow
        prep_kernel<<<128 + 32768 + 512, 256, 0, stream>>>(
            enc, Wk, queries, Wq, lengths, ench, wkh, pq);
        gemm_tanh_h3<<<4096, 256, 0, stream>>>(ench, wkh, pq, v, lengths, alg);
        softmax_kernel<<<NB, 256, 0, stream>>>(alg, lengths);
        hipMemsetAsync(ctx, 0, (size_t)NB * DIM * sizeof(float), stream);
        ctx_kernel_h4<<<dim3(32, NB), 256, 0, stream>>>(alg, ench, lengths, ctx);
    } else {
        pq_kernel<<<NB * DIM / 4, 256, 0, stream>>>(queries, Wq, pq);
        dim3 g2(512, 8);
        gemm_tanh_kernel<<<g2, 256, 0, stream>>>(enc, Wk, pq, v, lengths, alg);
        softmax_kernel<<<NB, 256, 0, stream>>>(alg, lengths);
        hipMemsetAsync(ctx, 0, (size_t)NB * DIM * sizeof(float), stream);
        ctx_kernel<<<dim3(16, NB), 256, 0, stream>>>(alg, enc, lengths, ctx);
    }
}

// Round 5
// 501.468 us; speedup vs baseline: 1.0408x; 1.0408x over previous
//
#include <hip/hip_runtime.h>
#include <hip/hip_bf16.h>

// Problem constants (from reference): N=32, T=2048, D_ENC=D_DEC=U=1024
#define NB 32
#define TD 2048
#define DIM 1024

typedef _Float16 v8h __attribute__((ext_vector_type(8)));
typedef _Float16 v4h __attribute__((ext_vector_type(4)));
typedef float    v4f __attribute__((ext_vector_type(4)));

__device__ __forceinline__ float ftanh(float x) {
    x = fminf(15.f, fmaxf(-15.f, x));
    float e = __expf(2.f * x);
    return (e - 1.f) / (e + 1.f);
}

__device__ __forceinline__ void gld_lds16(const void* g, void* l) {
    __builtin_amdgcn_global_load_lds(
        (const __attribute__((address_space(1))) unsigned int*)g,
        (__attribute__((address_space(3))) unsigned int*)l, 16, 0, 0);
}

// ---------------- K1 (fused): prep = pq (blocks 0..127) + cvt (blocks 128..33407) ----
// pq part: block b owns u-rows b*8..b*8+7 for ALL 32 n -> Wq read ONCE globally
// (4 MB vs old 128 MB). Placed first so it overlaps cvt's HBM shadow.
__global__ __launch_bounds__(256) void prep_kernel(
        const float* __restrict__ enc, const float* __restrict__ Wk,
        const float* __restrict__ queries, const float* __restrict__ Wq,
        const int* __restrict__ lengths,
        _Float16* __restrict__ ench, _Float16* __restrict__ wkh,
        float* __restrict__ pq) {
    int bid = blockIdx.x;
    if (bid < 128) {
        // ---- pq: 4 waves x 2 u-rows = 8 u per block ----
        int lane = threadIdx.x & 63;
        int wv   = threadIdx.x >> 6;
        int u    = bid * 8 + wv * 2;
        const float* w0 = Wq + (size_t)u * DIM;
        const float* w1 = w0 + DIM;
        // lane owns d-slices {j*256 + lane*4 .. +4}, coalesced float4
        float4 wq0[4], wq1[4];
#pragma unroll
        for (int j = 0; j < 4; ++j) {
            wq0[j] = *(const float4*)(w0 + j * 256 + lane * 4);
            wq1[j] = *(const float4*)(w1 + j * 256 + lane * 4);
        }
        for (int n = 0; n < NB; ++n) {
            const float* qn = queries + (size_t)n * DIM;
            float s0 = 0.f, s1 = 0.f;
#pragma unroll
            for (int j = 0; j < 4; ++j) {
                float4 qv = *(const float4*)(qn + j * 256 + lane * 4);
                s0 += qv.x * wq0[j].x + qv.y * wq0[j].y + qv.z * wq0[j].z + qv.w * wq0[j].w;
                s1 += qv.x * wq1[j].x + qv.y * wq1[j].y + qv.z * wq1[j].z + qv.w * wq1[j].w;
            }
#pragma unroll
            for (int off = 32; off >= 1; off >>= 1) {
                s0 += __shfl_xor(s0, off);
                s1 += __shfl_xor(s1, off);
            }
            if (lane == 0) {
                pq[(size_t)n * DIM + u]     = s0;
                pq[(size_t)n * DIM + u + 1] = s1;
            }
        }
        return;
    }
    // ---- cvt: f32 -> f16, 2 rows per block ----
    int cb = bid - 128;
    int local = threadIdx.x * 8;              // 0..2047 within the 2-row pair
    int rsub  = local >> 10;                  // 0 or 1
    int col   = local & 1023;
    const float* src;
    _Float16* dst;
    size_t row;
    if (cb < 32768) {
        row = (size_t)cb * 2 + rsub;          // enc row in [0, 65536)
        int n = (int)(row >> 11), t = (int)(row & 2047);
        if (t >= lengths[n]) return;          // masked row: never read downstream
        src = enc; dst = ench;
    } else {
        row = (size_t)(cb - 32768) * 2 + rsub;  // Wk row in [0,1024)
        src = Wk; dst = wkh;
    }
    const float4* s = (const float4*)(src + row * DIM + col);
    float4 a = s[0], b = s[1];
    v8h h;
    h[0] = (_Float16)a.x; h[1] = (_Float16)a.y; h[2] = (_Float16)a.z; h[3] = (_Float16)a.w;
    h[4] = (_Float16)b.x; h[5] = (_Float16)b.y; h[6] = (_Float16)b.z; h[7] = (_Float16)b.w;
    *(v8h*)(dst + row * DIM + col) = h;
}

// ---------------- K1 (fallback path): standalone pq ----------------
__global__ __launch_bounds__(256) void pq_kernel(const float* __restrict__ q,
                                                 const float* __restrict__ Wq,
                                                 float* __restrict__ pq) {
    int wid  = blockIdx.x * 4 + (threadIdx.x >> 6);
    int lane = threadIdx.x & 63;
    int n = wid >> 10;
    int u = wid & 1023;
    const float4* qr = (const float4*)(q  + (size_t)n * DIM);
    const float4* wr = (const float4*)(Wq + (size_t)u * DIM);
    float s = 0.f;
#pragma unroll
    for (int j = 0; j < 4; ++j) {
        int i = lane + 64 * j;
        float4 a = qr[i], b = wr[i];
        s += a.x * b.x + a.y * b.y + a.z * b.z + a.w * b.w;
    }
#pragma unroll
    for (int off = 32; off >= 1; off >>= 1) s += __shfl_xor(s, off);
    if (lane == 0) pq[(size_t)n * DIM + u] = s;
}

// ---------------- K2 (fast v4): m97-style single-buffer, BK=64, balanced swizzle ----
// grid = 4096 (1-D). Per block: one 128x128 output tile (bm, bn).
// XCD mapping: xcd = bid&7 (HW round-robin), j = bid>>3, bn = j&7, g = j>>3,
//   bm = 8g + ((xcd ^ g) & 7).
// Properties: (a) the 8 bn-blocks of one bm stay CONSECUTIVE on one XCD ->
// A-tile L2-resident across its 8 uses (round-3: FETCH 224->43 MB, keep);
// (b) tstart stratum of bm = 8(g&1) + (xcd^g): over any 16 g's, every XCD's
// summed stratum-survival weight is exactly 68/16 -> NO length-induced XCD
// imbalance (round-3 mapping gave XCD0 0.75 vs XCD7 0.31 -> 1.41x stretch).
// T2 swizzle: 0 bank conflicts (measured). Loop = m97 drain + TLP, unchanged.
__global__ __launch_bounds__(256) void gemm_tanh_h3(
        const _Float16* __restrict__ ench, const _Float16* __restrict__ wkh,
        const float* __restrict__ pq, const float* __restrict__ v,
        const int* __restrict__ lengths, float* __restrict__ weights) {
    const int bid = blockIdx.x;
    const int xcd = bid & 7;
    const int j   = bid >> 3;
    const int g   = j >> 3;
    const int bm  = (g << 3) | ((xcd ^ g) & 7);   // [0,512), balanced strata
    const int bn  = j & 7;
    const int rowBase = bm * 128;
    const int n = rowBase >> 11;
    const int tstart = rowBase & 2047;
    if (lengths[n] <= tstart) return;

    __shared__ _Float16 As[128 * 64];   // 16 KB
    __shared__ _Float16 Bs[128 * 64];   // 16 KB

    const int tid  = threadIdx.x;
    const int lane = tid & 63;
    const int wv   = tid >> 6;
    const int wm   = wv >> 1, wn = wv & 1;   // 2x2 waves, 64x64 each
    const int q4   = lane >> 4;
    const int l16  = lane & 15;

    // epilogue operands hoisted above the K-loop (independent of it)
    float pqv[4], vv[4];
#pragma unroll
    for (int nt = 0; nt < 4; ++nt) {
        int ug = bn * 128 + wn * 64 + nt * 16 + l16;
        pqv[nt] = pq[(size_t)n * DIM + ug];
        vv[nt]  = v[ug];
    }

    // staging: lane l -> row sr=l>>3, LDS slot sl=l&7; global slot pre-swizzled
    // sl^sr so that LDS[r][s] = G[r][s ^ (r&7)] with a LINEAR LDS dest (rule #21).
    const int sr  = lane >> 3;
    const int scs = (lane & 7) ^ sr;

    const _Float16* Ag = ench + (size_t)(rowBase + wv * 32 + sr) * DIM + scs * 8;
    const _Float16* Bg = wkh + (size_t)(bn * 128 + wv * 32 + sr) * DIM + scs * 8;
    _Float16* Al = &As[(wv * 32) * 64];
    _Float16* Bl = &Bs[(wv * 32) * 64];

    v4f acc[4][4];
    const v4f vz = {0.f, 0.f, 0.f, 0.f};
#pragma unroll
    for (int i = 0; i < 4; ++i)
#pragma unroll
        for (int j2 = 0; j2 < 4; ++j2) acc[i][j2] = vz;

    for (int k0 = 0; k0 < DIM; k0 += 64) {
        __syncthreads();                       // all reads of LDS done
#pragma unroll
        for (int jj = 0; jj < 4; ++jj) {
            gld_lds16(Ag + k0 + jj * 8 * DIM, Al + jj * 8 * 64);
            gld_lds16(Bg + k0 + jj * 8 * DIM, Bl + jj * 8 * 64);
        }
        __syncthreads();                       // drains vmcnt(0): tile visible

#pragma unroll
        for (int kk = 0; kk < 2; ++kk) {
            v8h a[4], b[4];
#pragma unroll
            for (int mt = 0; mt < 4; ++mt) {
                int r = wm * 64 + mt * 16 + l16;
                a[mt] = *(const v8h*)(&As[r * 64 + (((kk * 4 + q4) ^ (r & 7)) * 8)]);
            }
#pragma unroll
            for (int nt = 0; nt < 4; ++nt) {
                int r = wn * 64 + nt * 16 + l16;
                b[nt] = *(const v8h*)(&Bs[r * 64 + (((kk * 4 + q4) ^ (r & 7)) * 8)]);
            }
#pragma unroll
            for (int mt = 0; mt < 4; ++mt)
#pragma unroll
                for (int nt = 0; nt < 4; ++nt)
                    acc[mt][nt] = __builtin_amdgcn_mfma_f32_16x16x32_f16(
                        a[mt], b[nt], acc[mt][nt], 0, 0, 0);
        }
    }

#pragma unroll
    for (int mt = 0; mt < 4; ++mt) {
#pragma unroll
        for (int r = 0; r < 4; ++r) {
            float s = 0.f;
#pragma unroll
            for (int nt = 0; nt < 4; ++nt)
                s += ftanh(acc[mt][nt][r] + pqv[nt]) * vv[nt];
            s += __shfl_xor(s, 1);
            s += __shfl_xor(s, 2);
            s += __shfl_xor(s, 4);
            s += __shfl_xor(s, 8);
            if (l16 == 0) {
                int R = rowBase + wm * 64 + mt * 16 + q4 * 4 + r;
                atomicAdd(&weights[R], s);
            }
        }
    }
}

// ---------------- K2 (fallback): inline-convert f32 GEMM ----------------
__global__ __launch_bounds__(256) void gemm_tanh_kernel(
        const float* __restrict__ enc, const float* __restrict__ Wk,
        const float* __restrict__ pq,  const float* __restrict__ v,
        const int* __restrict__ lengths, float* __restrict__ weights) {
    const int bm = blockIdx.x;
    const int bn = blockIdx.y;
    const int rowBase = bm * 128;
    const int n = rowBase >> 11;
    const int tstart = rowBase & 2047;
    if (lengths[n] <= tstart) return;

    __shared__ _Float16 As[128 * 40];
    __shared__ _Float16 Bs[128 * 40];

    const int tid  = threadIdx.x;
    const int lane = tid & 63;
    const int wv   = tid >> 6;
    const int wm   = wv >> 1, wn = wv & 1;
    const int q4   = lane >> 4;
    const int l16  = lane & 15;

    v4f acc[4][4];
    const v4f vz = {0.f, 0.f, 0.f, 0.f};
#pragma unroll
    for (int i = 0; i < 4; ++i)
#pragma unroll
        for (int j = 0; j < 4; ++j) acc[i][j] = vz;

    const int srow = tid >> 3;
    const int skc  = (tid & 7) * 4;

    for (int k0 = 0; k0 < DIM; k0 += 32) {
        __syncthreads();
#pragma unroll
        for (int j = 0; j < 4; ++j) {
            int row = j * 32 + srow;
            float4 av = *(const float4*)(enc + (size_t)(rowBase + row) * DIM + k0 + skc);
            v4h ah;
            ah.x = (_Float16)av.x; ah.y = (_Float16)av.y;
            ah.z = (_Float16)av.z; ah.w = (_Float16)av.w;
            *(v4h*)(&As[row * 40 + skc]) = ah;
            float4 bv = *(const float4*)(Wk + (size_t)(bn * 128 + row) * DIM + k0 + skc);
            v4h bh;
            bh.x = (_Float16)bv.x; bh.y = (_Float16)bv.y;
            bh.z = (_Float16)bv.z; bh.w = (_Float16)bv.w;
            *(v4h*)(&Bs[row * 40 + skc]) = bh;
        }
        __syncthreads();

        v8h afr[4], bfr[4];
#pragma unroll
        for (int mt = 0; mt < 4; ++mt)
            afr[mt] = *(const v8h*)(&As[(wm * 64 + mt * 16 + l16) * 40 + q4 * 8]);
#pragma unroll
        for (int nt = 0; nt < 4; ++nt)
            bfr[nt] = *(const v8h*)(&Bs[(wn * 64 + nt * 16 + l16) * 40 + q4 * 8]);
#pragma unroll
        for (int mt = 0; mt < 4; ++mt)
#pragma unroll
            for (int nt = 0; nt < 4; ++nt)
                acc[mt][nt] = __builtin_amdgcn_mfma_f32_16x16x32_f16(
                    afr[mt], bfr[nt], acc[mt][nt], 0, 0, 0);
    }

    float pqv[4], vv[4];
#pragma unroll
    for (int nt = 0; nt < 4; ++nt) {
        int ug = bn * 128 + wn * 64 + nt * 16 + l16;
        pqv[nt] = pq[(size_t)n * DIM + ug];
        vv[nt]  = v[ug];
    }
#pragma unroll
    for (int mt = 0; mt < 4; ++mt) {
#pragma unroll
        for (int r = 0; r < 4; ++r) {
            float s = 0.f;
#pragma unroll
            for (int nt = 0; nt < 4; ++nt)
                s += ftanh(acc[mt][nt][r] + pqv[nt]) * vv[nt];
            s += __shfl_xor(s, 1);
            s += __shfl_xor(s, 2);
            s += __shfl_xor(s, 4);
            s += __shfl_xor(s, 8);
            if (l16 == 0) {
                int R = rowBase + wm * 64 + mt * 16 + q4 * 4 + r;
                atomicAdd(&weights[R], s);
            }
        }
    }
}

// ---------------- K3: masked softmax per n-row, in place ----------------
__global__ __launch_bounds__(256) void softmax_kernel(float* __restrict__ w,
                                                      const int* __restrict__ lengths) {
    int n = blockIdx.x;
    int len = lengths[n];
    float* row = w + (size_t)n * TD;
    int tid = threadIdx.x;
    float wv[8], ev[8];
    float mx = -INFINITY;
#pragma unroll
    for (int i = 0; i < 8; ++i) {
        int t = tid + i * 256;
        float x = row[t];
        x = (t < len) ? x : -INFINITY;
        wv[i] = x;
        mx = fmaxf(mx, x);
    }
#pragma unroll
    for (int off = 32; off >= 1; off >>= 1) mx = fmaxf(mx, __shfl_xor(mx, off));
    __shared__ float redm[4], reds[4];
    int lane = tid & 63, wvid = tid >> 6;
    if (lane == 0) redm[wvid] = mx;
    __syncthreads();
    mx = fmaxf(fmaxf(redm[0], redm[1]), fmaxf(redm[2], redm[3]));
    float sm = 0.f;
#pragma unroll
    for (int i = 0; i < 8; ++i) { ev[i] = __expf(wv[i] - mx); sm += ev[i]; }
#pragma unroll
    for (int off = 32; off >= 1; off >>= 1) sm += __shfl_xor(sm, off);
    if (lane == 0) reds[wvid] = sm;
    __syncthreads();
    sm = reds[0] + reds[1] + reds[2] + reds[3];
    float inv = 1.f / sm;
#pragma unroll
    for (int i = 0; i < 8; ++i) row[tid + i * 256] = ev[i] * inv;
}

// ---------------- K4 (fast v4): contexts, 64-t chunks, 2x parallelism ----------------
// 32 blocks per n -> ~2 active blocks/CU (was ~1), half-length dependency chains.
__global__ __launch_bounds__(256) void ctx_kernel_h4(const float* __restrict__ align,
                                                     const _Float16* __restrict__ ench,
                                                     const int* __restrict__ lengths,
                                                     float* __restrict__ ctx) {
    int n  = blockIdx.y;
    int t0 = blockIdx.x * 64;
    int len = lengths[n];
    if (len <= t0) return;
    int half = threadIdx.x >> 7;          // 0/1: t parity
    int col  = (threadIdx.x & 127) * 8;   // 8 cols -> 16B f16 loads
    float acc[8];
#pragma unroll
    for (int i = 0; i < 8; ++i) acc[i] = 0.f;
    int tend = min(t0 + 64, len);         // only converted (valid) rows
    const float* arow = align + (size_t)n * TD;
    const _Float16* ebase = ench + (size_t)n * TD * DIM + col;
#pragma unroll 2
    for (int t = t0 + half; t < tend; t += 2) {
        float a = arow[t];
        v8h e = *(const v8h*)(ebase + (size_t)t * DIM);
#pragma unroll
        for (int i = 0; i < 8; ++i) acc[i] += a * (float)e[i];
    }
    __shared__ float cred[DIM];
    if (half == 1) {
#pragma unroll
        for (int i = 0; i < 8; ++i) cred[col + i] = acc[i];
    }
    __syncthreads();
    if (half == 0) {
        float* c = ctx + (size_t)n * DIM + col;
#pragma unroll
        for (int i = 0; i < 8; ++i) atomicAdd(c + i, acc[i] + cred[col + i]);
    }
}

// ---------------- K4 (fallback): f32 enc ----------------
__global__ __launch_bounds__(256) void ctx_kernel(const float* __restrict__ align,
                                                  const float* __restrict__ enc,
                                                  const int* __restrict__ lengths,
                                                  float* __restrict__ ctx) {
    int n  = blockIdx.y;
    int t0 = blockIdx.x * 128;
    if (lengths[n] <= t0) return;
    int e = threadIdx.x * 4;
    float4 acc = make_float4(0.f, 0.f, 0.f, 0.f);
    const float* arow = align + (size_t)n * TD;
    const float* erow = enc + (size_t)n * TD * DIM;
    for (int tt = 0; tt < 128; ++tt) {
        int t = t0 + tt;
        float a = arow[t];
        if (a != 0.f) {
            float4 evv = *(const float4*)(erow + (size_t)t * DIM + e);
            acc.x += a * evv.x; acc.y += a * evv.y;
            acc.z += a * evv.z; acc.w += a * evv.w;
        }
    }
    float* c = ctx + (size_t)n * DIM + e;
    atomicAdd(c + 0, acc.x);
    atomicAdd(c + 1, acc.y);
    atomicAdd(c + 2, acc.z);
    atomicAdd(c + 3, acc.w);
}

extern "C" void kernel_launch(void* const* d_in, const int* in_sizes, int n_in,
                              void* d_out, int out_size, void* d_ws, size_t ws_size,
                              hipStream_t stream) {
    const float* queries = (const float*)d_in[0];   // [32,1,1024]
    const float* enc     = (const float*)d_in[1];   // [32,2048,1024]
    const int*   lengths = (const int*)d_in[2];     // [32]
    const float* v       = (const float*)d_in[3];   // [1024]
    const float* Wq      = (const float*)d_in[4];   // [1024,1024]
    const float* Wk      = (const float*)d_in[5];   // [1024,1024]

    float* out = (float*)d_out;
    float* ctx = out;                // [32,1024]  (also temp home of pq)
    float* alg = out + NB * DIM;     // [32,2048]  (weights -> alignments in place)
    float* pq  = ctx;                // pq fully consumed before ctx memset below
    (void)in_sizes; (void)n_in; (void)out_size;

    const size_t ench_elems = (size_t)NB * TD * DIM;
    const size_t need = (ench_elems + (size_t)DIM * DIM) * sizeof(_Float16);

    hipMemsetAsync(alg, 0, (size_t)NB * TD * sizeof(float), stream);

    if (ws_size >= need) {
        _Float16* ench = (_Float16*)d_ws;
        _Float16* wkh  = ench + ench_elems;
        // fused pq + cvt: pq blocks first so they overlap cvt's HBM shadow
        prep_kernel<<<128 + 32768 + 512, 256, 0, stream>>>(
            enc, Wk, queries, Wq, lengths, ench, wkh, pq);
        gemm_tanh_h3<<<4096, 256, 0, stream>>>(ench, wkh, pq, v, lengths, alg);
        softmax_kernel<<<NB, 256, 0, stream>>>(alg, lengths);
        hipMemsetAsync(ctx, 0, (size_t)NB * DIM * sizeof(float), stream);
        ctx_kernel_h4<<<dim3(32, NB), 256, 0, stream>>>(alg, ench, lengths, ctx);
    } else {
        pq_kernel<<<NB * DIM / 4, 256, 0, stream>>>(queries, Wq, pq);
        dim3 g2(512, 8);
        gemm_tanh_kernel<<<g2, 256, 0, stream>>>(enc, Wk, pq, v, lengths, alg);
        softmax_kernel<<<NB, 256, 0, stream>>>(alg, lengths);
        hipMemsetAsync(ctx, 0, (size_t)NB * DIM * sizeof(float), stream);
        ctx_kernel<<<dim3(16, NB), 256, 0, stream>>>(alg, enc, lengths, ctx);
    }
}